// Round 19
// baseline (61.003 us; speedup 1.0000x reference)
//
#include <hip/hip_runtime.h>

#define D    64
#define K    512
#define KH   256               // codes per k-half
#define QTOT (8 * 16384)
#define THR  0.001f            // 26 sigma of bf16x3 statistical error (proven r17/18)

typedef __attribute__((ext_vector_type(8))) short short8;   // 8 bf16 payloads (4 VGPRs)
typedef __attribute__((ext_vector_type(4))) short short4v;  // 4 bf16 payloads (8 B)
typedef __attribute__((ext_vector_type(4))) float f32x4;

__device__ __forceinline__ unsigned short f2bf(float f) {   // fp32 -> bf16 (RNE)
    unsigned u = __builtin_bit_cast(unsigned, f);
    u = u + 0x7FFFu + ((u >> 16) & 1u);
    return (unsigned short)(u >> 16);
}
__device__ __forceinline__ float bf2f(unsigned short h) {
    unsigned u = ((unsigned)h) << 16;
    return __builtin_bit_cast(float, u);
}

// ---- prep (proven rounds 14-18): esq + bf16 split of (-2*cb), 8 blocks ----
__global__ __launch_bounds__(512) void prep2b_kernel(const float* __restrict__ cb,
        float* __restrict__ esq, unsigned short* __restrict__ eh2,
        unsigned short* __restrict__ el2) {
    const int tid = threadIdx.x;
    const int b   = blockIdx.x;                 // 0..7
    const float4* cbv4 = (const float4*)cb;
    for (int c = b * 512 + tid; c < (K * D) / 4; c += 4096) {
        float4 v = cbv4[c];
        float vv[4] = {v.x, v.y, v.z, v.w};
        short4v hi, lo;
        #pragma unroll
        for (int j = 0; j < 4; ++j) {
            unsigned short hb = f2bf(vv[j]);
            float hf = bf2f(hb);
            unsigned short lb = f2bf(vv[j] - hf);
            hi[j] = (short)f2bf(-2.0f * hf);          // exact power-of-2 scaling
            lo[j] = (short)f2bf(-2.0f * bf2f(lb));
        }
        ((short4v*)eh2)[c] = hi;
        ((short4v*)el2)[c] = lo;
    }
    if (tid < 64) {                             // esq rows b*64 .. b*64+63
        const int row = b * 64 + tid;
        const float4* rp = (const float4*)(cb + (size_t)row * D);
        float s = 0.f;
        #pragma unroll
        for (int i = 0; i < 16; ++i) {
            float4 v = rp[i];
            s = fmaf(v.x, v.x, s); s = fmaf(v.y, v.y, s);
            s = fmaf(v.z, v.z, s); s = fmaf(v.w, v.w, s);
        }
        esq[row] = s;
    }
}

// ---- main: K-SPLIT. Each block: 256 queries x 256 codes (one k-half).
// LDS 66 KB -> 2 blocks/CU -> 8 waves/SIMD; phases desync across blocks.
// t-loop body verbatim from round 18 (6-MFMA chain, setprio, med3 min-track).
// Partials (m1,m2,i1) land in the output row itself (12 B at offset bh*12).
__global__ __launch_bounds__(1024, 8) void vq_half(
        const float* __restrict__ x, const float* __restrict__ g_esq,
        const unsigned short* __restrict__ eh2, const unsigned short* __restrict__ el2,
        float* __restrict__ out) {

    __shared__ unsigned short s_e[2][KH * D];   // this half's (-2*hi)/(-2*lo), 64 KB
    __shared__ float s_esq[KH];                 // 1 KB

    const int tid  = threadIdx.x;
    const int lane = tid & 63;
    const int qrow = lane & 15;                 // query col of C / code row of A
    const int kg   = lane >> 4;
    const int kg4  = kg * 4;
    const int wv   = __builtin_amdgcn_readfirstlane(tid >> 6);   // 0..15
    const int qb   = blockIdx.x & 511;          // query-group
    const int bh   = blockIdx.x >> 9;           // k-half 0/1
    const int kbase = bh * KH;                  // 0 or 256 (bit 8; disjoint from t,kg bits)
    const int qw   = qb * 256 + wv * 16;        // wave's 16 queries (qt=1)

    // stage this half's pre-split codebook into swizzled LDS (2 iters/thread)
    {
        const short8* src_h = (const short8*)eh2 + (size_t)bh * (KH * D / 8);
        const short8* src_l = (const short8*)el2 + (size_t)bh * (KH * D / 8);
        #pragma unroll
        for (int it = 0; it < 2; ++it) {
            int c = tid + it * 1024;            // 0..2047 local short8 index
            short8 hv = src_h[c];
            short8 lv = src_l[c];
            int byteoff = c * 16;
            int row     = byteoff >> 7;         // local code row 0..255
            int addr    = byteoff ^ ((row & 7) << 4);
            *(short8*)((char*)s_e[0] + addr) = hv;
            *(short8*)((char*)s_e[1] + addr) = lv;
        }
    }
    if (tid < KH) s_esq[tid] = g_esq[kbase + tid];
    __syncthreads();

    // B-fragments (qt=1): lane slot (kg, j) holds x[qw+qrow][h*32 + kg*8 + j].
    short8 xh[2], xl[2];
    #pragma unroll
    for (int h = 0; h < 2; ++h) {
        const float* p = x + (size_t)(qw + qrow) * D + h * 32 + kg * 8;
        float4 v0 = *(const float4*)p;
        float4 v1 = *(const float4*)(p + 4);
        float vv[8] = {v0.x, v0.y, v0.z, v0.w, v1.x, v1.y, v1.z, v1.w};
        short8 th, tl;
        #pragma unroll
        for (int j = 0; j < 8; ++j) {
            unsigned short hb = f2bf(vv[j]);
            th[j] = (short)hb;
            tl[j] = (short)f2bf(vv[j] - bf2f(hb));
        }
        xh[h] = th;
        xl[h] = tl;
    }

    float m1 = 3.4e38f, m2 = 3.4e38f;
    int   i1 = kbase;

    // loop-invariant swizzled base offsets (same algebra as rounds 11-18)
    const int swz = (qrow & 7) << 4;
    const int ob  = qrow * 128 + kg * 16;
    const char* ph = (const char*)s_e[0];
    const char* pl = (const char*)s_e[1];
    const int o0 = ob ^ swz;
    const int o1 = (ob + 64) ^ swz;
    const float* pq = s_esq + kg4;

    #pragma unroll
    for (int t = 0; t < 16; ++t) {
        short8 eh0 = *(const short8*)(ph + o0 + t * 2048);
        short8 eh1 = *(const short8*)(ph + o1 + t * 2048);
        short8 el0 = *(const short8*)(pl + o0 + t * 2048);
        short8 el1 = *(const short8*)(pl + o1 + t * 2048);
        f32x4 eqv  = *(const f32x4*)(pq + t * 16);

        __builtin_amdgcn_s_setprio(1);
        f32x4 a0 = eqv;                         // C-init = esq; -2 in codebook -> d2 proxy
        a0 = __builtin_amdgcn_mfma_f32_16x16x32_bf16(eh0, xh[0], a0, 0, 0, 0);
        a0 = __builtin_amdgcn_mfma_f32_16x16x32_bf16(eh1, xh[1], a0, 0, 0, 0);
        a0 = __builtin_amdgcn_mfma_f32_16x16x32_bf16(eh0, xl[0], a0, 0, 0, 0);
        a0 = __builtin_amdgcn_mfma_f32_16x16x32_bf16(eh1, xl[1], a0, 0, 0, 0);
        a0 = __builtin_amdgcn_mfma_f32_16x16x32_bf16(el0, xh[0], a0, 0, 0, 0);
        a0 = __builtin_amdgcn_mfma_f32_16x16x32_bf16(el1, xh[1], a0, 0, 0, 0);
        __builtin_amdgcn_s_setprio(0);

        #pragma unroll
        for (int r = 0; r < 4; ++r) {           // med3 min-track (proven r18)
            float dd = a0[r];
            int   kc = kbase | (t * 16) | (kg4 + r);   // disjoint bits
            bool  lt = dd < m1;                  // uses OLD m1
            m2 = fminf(fmaxf(m1, dd), m2);
            m1 = fminf(m1, dd);
            i1 = lt ? kc : i1;                   // strict < => first index wins
        }
    }

    // combine (m1,i1,m2) across the 4 k-groups holding each query
    #pragma unroll
    for (int off = 16; off <= 32; off <<= 1) {
        float om1 = __shfl_xor(m1, off, 64);
        float om2 = __shfl_xor(m2, off, 64);
        int   oi  = __shfl_xor(i1, off, 64);
        bool  lt  = om1 < m1;
        float loser = lt ? m1 : om1;
        m2 = fminf(fminf(m2, om2), loser);
        m1 = lt ? om1 : m1;
        i1 = lt ? oi  : i1;
    }

    // write this half's partial (m1,m2,i1) into the output row (12 B @ bh*12)
    if (lane < 16) {
        float* row = out + (size_t)(qw + lane) * D + bh * 3;
        row[0] = m1;
        row[1] = m2;
        row[2] = __builtin_bit_cast(float, i1);
    }
}

// ---- combine halves + rescan + emit. One wave per 16 queries. ----
__global__ __launch_bounds__(256) void combine_emit(
        const float* __restrict__ x, const float* __restrict__ cb,
        const float* __restrict__ esq, float* __restrict__ out) {

    const int tid  = threadIdx.x;
    const int lane = tid & 63;
    const int qrow = lane & 15;
    const int kg   = lane >> 4;
    const int wv   = __builtin_amdgcn_readfirstlane(tid >> 6);   // 0..3
    const int qw   = blockIdx.x * 64 + wv * 16;
    const size_t q = (size_t)(qw + qrow);

    // all 4 kg-lanes of a query load both partials (use forces vmcnt wait
    // before the overwriting emit stores -> no read/write race)
    float* row = out + q * D;
    float m1a = row[0], m2a = row[1];
    int   ia  = __builtin_bit_cast(int, row[2]);
    float m1b = row[3], m2b = row[4];
    int   ib  = __builtin_bit_cast(int, row[5]);

    // half-0 first + strict < keeps globally-first index on ties
    bool  lt = m1b < m1a;
    float m1 = lt ? m1b : m1a;
    int   i1 = lt ? ib  : ia;
    float loser = lt ? m1a : m1b;
    float m2 = fminf(fminf(m2a, m2b), loser);

    // exact fp32 rescan when top-2 gap <= THR (proven form; esq from global)
    {
        bool flag = (m2 - m1) <= THR;
        unsigned long long mask = __ballot(flag && (lane < 16));
        while (mask) {
            int ql = __ffsll(mask) - 1;
            mask &= mask - 1;
            int qf = qw + ql;                           // wave-uniform
            const float* xq = x + (size_t)qf * D;
            float bb = 3.4e38f;
            int   bq = 0;
            #pragma unroll 1
            for (int c0 = 0; c0 < 8; ++c0) {
                int kc = lane * 8 + c0;
                const float4* ep = (const float4*)(cb + (size_t)kc * D);
                float a = 0.f;
                #pragma unroll
                for (int i = 0; i < 16; ++i) {
                    float4 e = ep[i];
                    a = fmaf(xq[4 * i + 0], e.x, a);
                    a = fmaf(xq[4 * i + 1], e.y, a);
                    a = fmaf(xq[4 * i + 2], e.z, a);
                    a = fmaf(xq[4 * i + 3], e.w, a);
                }
                float dd = fmaf(-2.f, a, esq[kc]);
                if (dd < bb) { bb = dd; bq = kc; }      // ascending kc: first wins
            }
            #pragma unroll
            for (int off = 1; off < 64; off <<= 1) {    // min-reduce, first-index tie-break
                float ob = __shfl_xor(bb, off, 64);
                int   oq = __shfl_xor(bq, off, 64);
                if (ob < bb || (ob == bb && oq < bq)) { bb = ob; bq = oq; }
            }
            if (qrow == ql) i1 = bq;
        }
    }

    // emit: overwrite the row with cb[i1]; lane (qrow,kg) writes 64 B
    const float4* src = (const float4*)(cb + (size_t)i1 * D) + kg * 4;
    float4*       dst = (float4*)row + kg * 4;
    #pragma unroll
    for (int s = 0; s < 4; ++s) dst[s] = src[s];
}

// ================= SAFE fallback (no ws): round-4 kernel verbatim (proven) =================
__global__ __launch_bounds__(512) void vq_mfma(
        const float* __restrict__ x, const float* __restrict__ cb,
        float* __restrict__ out) {

    __shared__ unsigned short s_e[2][K * D];
    __shared__ float s_esq[K];

    const int tid  = threadIdx.x;
    const int lane = tid & 63;
    const int qrow = lane & 15;
    const int kg   = lane >> 4;
    const int wv   = __builtin_amdgcn_readfirstlane(tid >> 6);
    const int qw   = blockIdx.x * 512 + wv * 64;

    const float4* cbv4 = (const float4*)cb;
    for (int c = tid; c < (K * D) / 4; c += 512) {
        float4 v = cbv4[c];
        float vv[4] = {v.x, v.y, v.z, v.w};
        short4v hi, lo;
        #pragma unroll
        for (int j = 0; j < 4; ++j) {
            unsigned short hb = f2bf(vv[j]);
            hi[j] = (short)hb;
            lo[j] = (short)f2bf(vv[j] - bf2f(hb));
        }
        int byteoff = c * 8;
        int row     = byteoff >> 7;
        int addr    = byteoff ^ ((row & 7) << 4);
        *(short4v*)((char*)s_e[0] + addr) = hi;
        *(short4v*)((char*)s_e[1] + addr) = lo;
    }
    {
        float s = 0.f;
        #pragma unroll
        for (int d = 0; d < D; ++d) {
            float v = cb[tid * D + d];
            s = fmaf(v, v, s);
        }
        s_esq[tid] = s;
    }
    __syncthreads();

    short8 xh[4][2], xl[4][2];
    #pragma unroll
    for (int qt = 0; qt < 4; ++qt) {
        #pragma unroll
        for (int h = 0; h < 2; ++h) {
            const float* p = x + (size_t)(qw + qt * 16 + qrow) * D + h * 32 + kg * 8;
            float4 v0 = *(const float4*)p;
            float4 v1 = *(const float4*)(p + 4);
            float vv[8] = {v0.x, v0.y, v0.z, v0.w, v1.x, v1.y, v1.z, v1.w};
            short8 th, tl;
            #pragma unroll
            for (int j = 0; j < 8; ++j) {
                unsigned short hb = f2bf(vv[j]);
                th[j] = (short)hb;
                tl[j] = (short)f2bf(vv[j] - bf2f(hb));
            }
            xh[qt][h] = th;
            xl[qt][h] = tl;
        }
    }

    float m1[4], m2[4];
    int   i1[4];
    #pragma unroll
    for (int qt = 0; qt < 4; ++qt) { m1[qt] = 3.4e38f; m2[qt] = 3.4e38f; i1[qt] = 0; }

    const f32x4 zacc = {0.f, 0.f, 0.f, 0.f};

    for (int t = 0; t < 32; ++t) {
        const int row  = t * 16 + qrow;
        const int swz  = (row & 7) << 4;
        const int off0 = row * 128 + kg * 16;
        short8 eh0 = *(const short8*)((const char*)s_e[0] + ((off0     ) ^ swz));
        short8 eh1 = *(const short8*)((const char*)s_e[0] + ((off0 + 64) ^ swz));
        short8 el0 = *(const short8*)((const char*)s_e[1] + ((off0     ) ^ swz));
        short8 el1 = *(const short8*)((const char*)s_e[1] + ((off0 + 64) ^ swz));
        f32x4 eq = *(const f32x4*)(s_esq + t * 16 + kg * 4);

        #pragma unroll
        for (int qt = 0; qt < 4; ++qt) {
            f32x4 acc;
            asm volatile(
                "s_nop 3\n\t"
                "v_mfma_f32_16x16x32_bf16 %0, %1, %5, %9\n\t"
                "v_mfma_f32_16x16x32_bf16 %0, %2, %6, %0\n\t"
                "v_mfma_f32_16x16x32_bf16 %0, %1, %7, %0\n\t"
                "v_mfma_f32_16x16x32_bf16 %0, %2, %8, %0\n\t"
                "v_mfma_f32_16x16x32_bf16 %0, %3, %5, %0\n\t"
                "v_mfma_f32_16x16x32_bf16 %0, %4, %6, %0\n\t"
                "s_nop 7\n\t"
                "s_nop 7"
                : "=&v"(acc)
                : "v"(eh0), "v"(eh1), "v"(el0), "v"(el1),
                  "v"(xh[qt][0]), "v"(xh[qt][1]), "v"(xl[qt][0]), "v"(xl[qt][1]),
                  "v"(zacc));
            #pragma unroll
            for (int r = 0; r < 4; ++r) {
                float dd = fmaf(-2.f, acc[r], eq[r]);
                int   kc = t * 16 + kg * 4 + r;
                bool  lt = dd < m1[qt];
                m2[qt] = lt ? m1[qt] : fminf(m2[qt], dd);
                m1[qt] = lt ? dd : m1[qt];
                i1[qt] = lt ? kc : i1[qt];
            }
        }
    }

    #pragma unroll
    for (int qt = 0; qt < 4; ++qt) {
        #pragma unroll
        for (int off = 16; off <= 32; off <<= 1) {
            float om1 = __shfl_xor(m1[qt], off, 64);
            float om2 = __shfl_xor(m2[qt], off, 64);
            int   oi  = __shfl_xor(i1[qt], off, 64);
            bool  lt  = om1 < m1[qt];
            float loser = lt ? m1[qt] : om1;
            m2[qt] = fminf(fminf(m2[qt], om2), loser);
            m1[qt] = lt ? om1 : m1[qt];
            i1[qt] = lt ? oi  : i1[qt];
        }
    }

    #pragma unroll
    for (int qt = 0; qt < 4; ++qt) {
        bool flag = (m2[qt] - m1[qt]) <= 0.008f;
        unsigned long long mask = __ballot(flag && (lane < 16));
        while (mask) {
            int ql = __ffsll(mask) - 1;
            mask &= mask - 1;
            int qf = qw + qt * 16 + ql;
            const float* xq = x + (size_t)qf * D;
            float bb = 3.4e38f;
            int   bq = 0;
            #pragma unroll 1
            for (int c0 = 0; c0 < 8; ++c0) {
                int kc = lane * 8 + c0;
                const float4* ep = (const float4*)(cb + (size_t)kc * D);
                float a = 0.f;
                #pragma unroll
                for (int i = 0; i < 16; ++i) {
                    float4 e = ep[i];
                    a = fmaf(xq[4 * i + 0], e.x, a);
                    a = fmaf(xq[4 * i + 1], e.y, a);
                    a = fmaf(xq[4 * i + 2], e.z, a);
                    a = fmaf(xq[4 * i + 3], e.w, a);
                }
                float dd = fmaf(-2.f, a, s_esq[kc]);
                if (dd < bb) { bb = dd; bq = kc; }
            }
            #pragma unroll
            for (int off = 1; off < 64; off <<= 1) {
                float ob = __shfl_xor(bb, off, 64);
                int   oq = __shfl_xor(bq, off, 64);
                if (ob < bb || (ob == bb && oq < bq)) { bb = ob; bq = oq; }
            }
            if (qrow == ql) i1[qt] = bq;
        }
    }

    #pragma unroll
    for (int qt = 0; qt < 4; ++qt) {
        size_t q = (size_t)(qw + qt * 16 + qrow);
        const float4* src = (const float4*)(cb + (size_t)i1[qt] * D) + kg * 4;
        float4*       dst = (float4*)(out + q * D) + kg * 4;
        #pragma unroll
        for (int s = 0; s < 4; ++s) dst[s] = src[s];
    }
}

extern "C" void kernel_launch(void* const* d_in, const int* in_sizes, int n_in,
                              void* d_out, int out_size, void* d_ws, size_t ws_size,
                              hipStream_t stream) {
    const float* x   = (const float*)d_in[0];   // [8,16384,64]
    const float* cb  = (const float*)d_in[1];   // [512,64]
    float*       out = (float*)d_out;           // [8,16384,1,64]

    const size_t need = 2048 + (size_t)K * D * 2 * 2;   // esq + eh2 + el2 = 133120 B
    if (ws_size >= need) {
        float*          esq = (float*)d_ws;
        unsigned short* eh2 = (unsigned short*)((char*)d_ws + 2048);
        unsigned short* el2 = (unsigned short*)((char*)d_ws + 2048 + K * D * 2);
        prep2b_kernel<<<8, 512, 0, stream>>>(cb, esq, eh2, el2);
        vq_half<<<1024, 1024, 0, stream>>>(x, esq, eh2, el2, out);
        combine_emit<<<QTOT / 64, 256, 0, stream>>>(x, cb, esq, out);
    } else {
        vq_mfma<<<QTOT / 512, 512, 0, stream>>>(x, cb, out);
    }
}

// Round 20
// 48.368 us; speedup vs baseline: 1.2612x; 1.2612x over previous
//
#include <hip/hip_runtime.h>

#define D    64
#define K    512
#define QTOT (8 * 16384)
#define THR  0.001f   // 26 sigma of bf16x3 statistical error (proven round 17)

typedef __attribute__((ext_vector_type(8))) short short8;   // 8 bf16 payloads (4 VGPRs)
typedef __attribute__((ext_vector_type(4))) short short4v;  // 4 bf16 payloads (8 B)
typedef __attribute__((ext_vector_type(4))) float f32x4;

__device__ __forceinline__ unsigned short f2bf(float f) {   // fp32 -> bf16 (RNE)
    unsigned u = __builtin_bit_cast(unsigned, f);
    u = u + 0x7FFFu + ((u >> 16) & 1u);
    return (unsigned short)(u >> 16);
}
__device__ __forceinline__ float bf2f(unsigned short h) {
    unsigned u = ((unsigned)h) << 16;
    return __builtin_bit_cast(float, u);
}

// ---- prep (proven rounds 14-18): esq + bf16 split of (-2*cb), 8 blocks ----
__global__ __launch_bounds__(512) void prep2b_kernel(const float* __restrict__ cb,
        float* __restrict__ esq, unsigned short* __restrict__ eh2,
        unsigned short* __restrict__ el2) {
    const int tid = threadIdx.x;
    const int b   = blockIdx.x;                 // 0..7
    const float4* cbv4 = (const float4*)cb;
    for (int c = b * 512 + tid; c < (K * D) / 4; c += 4096) {
        float4 v = cbv4[c];
        float vv[4] = {v.x, v.y, v.z, v.w};
        short4v hi, lo;
        #pragma unroll
        for (int j = 0; j < 4; ++j) {
            unsigned short hb = f2bf(vv[j]);
            float hf = bf2f(hb);
            unsigned short lb = f2bf(vv[j] - hf);
            hi[j] = (short)f2bf(-2.0f * hf);          // exact power-of-2 scaling
            lo[j] = (short)f2bf(-2.0f * bf2f(lb));
        }
        ((short4v*)eh2)[c] = hi;
        ((short4v*)el2)[c] = lo;
    }
    if (tid < 64) {                             // esq rows b*64 .. b*64+63
        const int row = b * 64 + tid;
        const float4* rp = (const float4*)(cb + (size_t)row * D);
        float s = 0.f;
        #pragma unroll
        for (int i = 0; i < 16; ++i) {
            float4 v = rp[i];
            s = fmaf(v.x, v.x, s); s = fmaf(v.y, v.y, s);
            s = fmaf(v.z, v.z, s); s = fmaf(v.w, v.w, s);
        }
        esq[row] = s;
    }
}

// ---- main: round-18 vq_mfma12 VERBATIM (48.5us proven best): 1024 thr =
// 16 waves (4/SIMD), qt=2, LDS-resident (-2x) 3-plane bf16 codebook, full
// unroll + hoisted swizzle, C-init=esq, setprio around interleaved a0/a1
// MFMA burst, med3 min-track, THR=0.001 exact-fp32 rescan. ----
__global__ __launch_bounds__(1024) void vq_mfma12(
        const float* __restrict__ x, const float* __restrict__ cb,
        const float* __restrict__ g_esq, const unsigned short* __restrict__ eh2,
        const unsigned short* __restrict__ el2, float* __restrict__ out) {

    __shared__ unsigned short s_e[2][K * D];   // (-2*hi)/(-2*lo), XOR-swizzled
    __shared__ float s_esq[K];

    const int tid  = threadIdx.x;
    const int lane = tid & 63;
    const int qrow = lane & 15;                 // query col of C / code row of A
    const int kg   = lane >> 4;
    const int kg4  = kg * 4;
    const int wv   = __builtin_amdgcn_readfirstlane(tid >> 6);   // 0..15
    const int qw   = blockIdx.x * 512 + wv * 32;   // wave's first query (qt=2 x 16)

    // stage pre-split (-2x) codebook into swizzled LDS (4 iters/thread)
    for (int c = tid; c < (K * D) / 8; c += 1024) {
        short8 hv = ((const short8*)eh2)[c];
        short8 lv = ((const short8*)el2)[c];
        int byteoff = c * 16;
        int row     = byteoff >> 7;             // 128 B per code row
        int addr    = byteoff ^ ((row & 7) << 4);
        *(short8*)((char*)s_e[0] + addr) = hv;
        *(short8*)((char*)s_e[1] + addr) = lv;
    }
    if (tid < K) s_esq[tid] = g_esq[tid];
    __syncthreads();

    // B-fragments: lane slot (kg, j) holds x[query][h*32 + kg*8 + j], hi/lo split.
    // A-slots use the same (kg, j) -> dim map, so pairing is k-order independent.
    short8 xh[2][2], xl[2][2];
    #pragma unroll
    for (int qt = 0; qt < 2; ++qt) {
        #pragma unroll
        for (int h = 0; h < 2; ++h) {
            const float* p = x + (size_t)(qw + qt * 16 + qrow) * D + h * 32 + kg * 8;
            float4 v0 = *(const float4*)p;
            float4 v1 = *(const float4*)(p + 4);
            float vv[8] = {v0.x, v0.y, v0.z, v0.w, v1.x, v1.y, v1.z, v1.w};
            short8 th, tl;
            #pragma unroll
            for (int j = 0; j < 8; ++j) {
                unsigned short hb = f2bf(vv[j]);
                th[j] = (short)hb;
                tl[j] = (short)f2bf(vv[j] - bf2f(hb));
            }
            xh[qt][h] = th;
            xl[qt][h] = tl;
        }
    }

    float m1[2], m2[2];
    int   i1[2];
    #pragma unroll
    for (int qt = 0; qt < 2; ++qt) { m1[qt] = 3.4e38f; m2[qt] = 3.4e38f; i1[qt] = 0; }

    // loop-invariant swizzled base offsets: (t*16+qrow)&7 == qrow&7, and the
    // per-t term t*2048 shares no bits with the XOR mask (bits 4-6).
    const int swz = (qrow & 7) << 4;
    const int ob  = qrow * 128 + kg * 16;
    const char* ph = (const char*)s_e[0];
    const char* pl = (const char*)s_e[1];
    const int o0 = ob ^ swz;
    const int o1 = (ob + 64) ^ swz;
    const float* pq = s_esq + kg4;

    #pragma unroll
    for (int t = 0; t < 32; ++t) {
        // all five LDS reads: base + compile-time immediate (ds offset field)
        short8 eh0 = *(const short8*)(ph + o0 + t * 2048);
        short8 eh1 = *(const short8*)(ph + o1 + t * 2048);
        short8 el0 = *(const short8*)(pl + o0 + t * 2048);
        short8 el1 = *(const short8*)(pl + o1 + t * 2048);
        f32x4 eqv  = *(const f32x4*)(pq + t * 16);

        __builtin_amdgcn_s_setprio(1);          // favor this wave through the MFMA burst
        f32x4 a0 = eqv, a1 = eqv;               // C-init = esq; -2 in codebook -> d2 proxy
        a0 = __builtin_amdgcn_mfma_f32_16x16x32_bf16(eh0, xh[0][0], a0, 0, 0, 0);
        a1 = __builtin_amdgcn_mfma_f32_16x16x32_bf16(eh0, xh[1][0], a1, 0, 0, 0);
        a0 = __builtin_amdgcn_mfma_f32_16x16x32_bf16(eh1, xh[0][1], a0, 0, 0, 0);
        a1 = __builtin_amdgcn_mfma_f32_16x16x32_bf16(eh1, xh[1][1], a1, 0, 0, 0);
        a0 = __builtin_amdgcn_mfma_f32_16x16x32_bf16(eh0, xl[0][0], a0, 0, 0, 0);
        a1 = __builtin_amdgcn_mfma_f32_16x16x32_bf16(eh0, xl[1][0], a1, 0, 0, 0);
        a0 = __builtin_amdgcn_mfma_f32_16x16x32_bf16(eh1, xl[0][1], a0, 0, 0, 0);
        a1 = __builtin_amdgcn_mfma_f32_16x16x32_bf16(eh1, xl[1][1], a1, 0, 0, 0);
        a0 = __builtin_amdgcn_mfma_f32_16x16x32_bf16(el0, xh[0][0], a0, 0, 0, 0);
        a1 = __builtin_amdgcn_mfma_f32_16x16x32_bf16(el0, xh[1][0], a1, 0, 0, 0);
        a0 = __builtin_amdgcn_mfma_f32_16x16x32_bf16(el1, xh[0][1], a0, 0, 0, 0);
        a1 = __builtin_amdgcn_mfma_f32_16x16x32_bf16(el1, xh[1][1], a1, 0, 0, 0);
        __builtin_amdgcn_s_setprio(0);

        #pragma unroll
        for (int r = 0; r < 4; ++r) {           // min-track qt=0 (med3 m2 form)
            float dd = a0[r];
            int   kc = (t * 16) | (kg4 + r);
            bool  lt = dd < m1[0];              // uses OLD m1
            m2[0] = fminf(fmaxf(m1[0], dd), m2[0]);   // 2nd-min, no vcc dependency
            m1[0] = lt ? dd : m1[0];
            i1[0] = lt ? kc : i1[0];            // strict < => first index wins
        }
        #pragma unroll
        for (int r = 0; r < 4; ++r) {           // min-track qt=1
            float dd = a1[r];
            int   kc = (t * 16) | (kg4 + r);
            bool  lt = dd < m1[1];
            m2[1] = fminf(fmaxf(m1[1], dd), m2[1]);
            m1[1] = lt ? dd : m1[1];
            i1[1] = lt ? kc : i1[1];
        }
    }

    // combine (m1,i1,m2) across the 4 k-groups holding each query
    #pragma unroll
    for (int qt = 0; qt < 2; ++qt) {
        #pragma unroll
        for (int off = 16; off <= 32; off <<= 1) {
            float om1 = __shfl_xor(m1[qt], off, 64);
            float om2 = __shfl_xor(m2[qt], off, 64);
            int   oi  = __shfl_xor(i1[qt], off, 64);
            bool  lt  = om1 < m1[qt];
            float loser = lt ? m1[qt] : om1;
            m2[qt] = fminf(fminf(m2[qt], om2), loser);
            m1[qt] = lt ? om1 : m1[qt];
            i1[qt] = lt ? oi  : i1[qt];
        }
    }

    // exact fp32 rescan when top-2 gap <= THR: fp32 argmin guaranteed;
    // approx ties (gap 0) also land here -> first-index restored.
    #pragma unroll
    for (int qt = 0; qt < 2; ++qt) {
        bool flag = (m2[qt] - m1[qt]) <= THR;
        unsigned long long mask = __ballot(flag && (lane < 16));
        while (mask) {
            int ql = __ffsll(mask) - 1;
            mask &= mask - 1;
            int qf = qw + qt * 16 + ql;                 // wave-uniform
            const float* xq = x + (size_t)qf * D;
            float bb = 3.4e38f;
            int   bq = 0;
            #pragma unroll 1
            for (int c0 = 0; c0 < 8; ++c0) {
                int kc = lane * 8 + c0;
                const float4* ep = (const float4*)(cb + (size_t)kc * D);
                float a = 0.f;
                #pragma unroll
                for (int i = 0; i < 16; ++i) {
                    float4 e = ep[i];
                    a = fmaf(xq[4 * i + 0], e.x, a);
                    a = fmaf(xq[4 * i + 1], e.y, a);
                    a = fmaf(xq[4 * i + 2], e.z, a);
                    a = fmaf(xq[4 * i + 3], e.w, a);
                }
                float dd = fmaf(-2.f, a, s_esq[kc]);
                if (dd < bb) { bb = dd; bq = kc; }      // ascending kc: first index wins
            }
            #pragma unroll
            for (int off = 1; off < 64; off <<= 1) {    // min-reduce, first-index tie-break
                float ob = __shfl_xor(bb, off, 64);
                int   oq = __shfl_xor(bq, off, 64);
                if (ob < bb || (ob == bb && oq < bq)) { bb = ob; bq = oq; }
            }
            if (qrow == ql) i1[qt] = bq;
        }
    }

    // emit: out[q] = cb[i1]; lane (qrow,kg) writes 64 B of query qrow's row
    #pragma unroll
    for (int qt = 0; qt < 2; ++qt) {
        size_t q = (size_t)(qw + qt * 16 + qrow);
        const float4* src = (const float4*)(cb + (size_t)i1[qt] * D) + kg * 4;
        float4*       dst = (float4*)(out + q * D) + kg * 4;
        #pragma unroll
        for (int s = 0; s < 4; ++s) dst[s] = src[s];
    }
}

// ================= SAFE fallback (no ws): round-4 kernel verbatim (proven) =================
__global__ __launch_bounds__(512) void vq_mfma(
        const float* __restrict__ x, const float* __restrict__ cb,
        float* __restrict__ out) {

    __shared__ unsigned short s_e[2][K * D];
    __shared__ float s_esq[K];

    const int tid  = threadIdx.x;
    const int lane = tid & 63;
    const int qrow = lane & 15;
    const int kg   = lane >> 4;
    const int wv   = __builtin_amdgcn_readfirstlane(tid >> 6);
    const int qw   = blockIdx.x * 512 + wv * 64;

    const float4* cbv4 = (const float4*)cb;
    for (int c = tid; c < (K * D) / 4; c += 512) {
        float4 v = cbv4[c];
        float vv[4] = {v.x, v.y, v.z, v.w};
        short4v hi, lo;
        #pragma unroll
        for (int j = 0; j < 4; ++j) {
            unsigned short hb = f2bf(vv[j]);
            hi[j] = (short)hb;
            lo[j] = (short)f2bf(vv[j] - bf2f(hb));
        }
        int byteoff = c * 8;
        int row     = byteoff >> 7;
        int addr    = byteoff ^ ((row & 7) << 4);
        *(short4v*)((char*)s_e[0] + addr) = hi;
        *(short4v*)((char*)s_e[1] + addr) = lo;
    }
    {
        float s = 0.f;
        #pragma unroll
        for (int d = 0; d < D; ++d) {
            float v = cb[tid * D + d];
            s = fmaf(v, v, s);
        }
        s_esq[tid] = s;
    }
    __syncthreads();

    short8 xh[4][2], xl[4][2];
    #pragma unroll
    for (int qt = 0; qt < 4; ++qt) {
        #pragma unroll
        for (int h = 0; h < 2; ++h) {
            const float* p = x + (size_t)(qw + qt * 16 + qrow) * D + h * 32 + kg * 8;
            float4 v0 = *(const float4*)p;
            float4 v1 = *(const float4*)(p + 4);
            float vv[8] = {v0.x, v0.y, v0.z, v0.w, v1.x, v1.y, v1.z, v1.w};
            short8 th, tl;
            #pragma unroll
            for (int j = 0; j < 8; ++j) {
                unsigned short hb = f2bf(vv[j]);
                th[j] = (short)hb;
                tl[j] = (short)f2bf(vv[j] - bf2f(hb));
            }
            xh[qt][h] = th;
            xl[qt][h] = tl;
        }
    }

    float m1[4], m2[4];
    int   i1[4];
    #pragma unroll
    for (int qt = 0; qt < 4; ++qt) { m1[qt] = 3.4e38f; m2[qt] = 3.4e38f; i1[qt] = 0; }

    const f32x4 zacc = {0.f, 0.f, 0.f, 0.f};

    for (int t = 0; t < 32; ++t) {
        const int row  = t * 16 + qrow;
        const int swz  = (row & 7) << 4;
        const int off0 = row * 128 + kg * 16;
        short8 eh0 = *(const short8*)((const char*)s_e[0] + ((off0     ) ^ swz));
        short8 eh1 = *(const short8*)((const char*)s_e[0] + ((off0 + 64) ^ swz));
        short8 el0 = *(const short8*)((const char*)s_e[1] + ((off0     ) ^ swz));
        short8 el1 = *(const short8*)((const char*)s_e[1] + ((off0 + 64) ^ swz));
        f32x4 eq = *(const f32x4*)(s_esq + t * 16 + kg * 4);

        #pragma unroll
        for (int qt = 0; qt < 4; ++qt) {
            f32x4 acc;
            asm volatile(
                "s_nop 3\n\t"
                "v_mfma_f32_16x16x32_bf16 %0, %1, %5, %9\n\t"
                "v_mfma_f32_16x16x32_bf16 %0, %2, %6, %0\n\t"
                "v_mfma_f32_16x16x32_bf16 %0, %1, %7, %0\n\t"
                "v_mfma_f32_16x16x32_bf16 %0, %2, %8, %0\n\t"
                "v_mfma_f32_16x16x32_bf16 %0, %3, %5, %0\n\t"
                "v_mfma_f32_16x16x32_bf16 %0, %4, %6, %0\n\t"
                "s_nop 7\n\t"
                "s_nop 7"
                : "=&v"(acc)
                : "v"(eh0), "v"(eh1), "v"(el0), "v"(el1),
                  "v"(xh[qt][0]), "v"(xh[qt][1]), "v"(xl[qt][0]), "v"(xl[qt][1]),
                  "v"(zacc));
            #pragma unroll
            for (int r = 0; r < 4; ++r) {
                float dd = fmaf(-2.f, acc[r], eq[r]);
                int   kc = t * 16 + kg * 4 + r;
                bool  lt = dd < m1[qt];
                m2[qt] = lt ? m1[qt] : fminf(m2[qt], dd);
                m1[qt] = lt ? dd : m1[qt];
                i1[qt] = lt ? kc : i1[qt];
            }
        }
    }

    #pragma unroll
    for (int qt = 0; qt < 4; ++qt) {
        #pragma unroll
        for (int off = 16; off <= 32; off <<= 1) {
            float om1 = __shfl_xor(m1[qt], off, 64);
            float om2 = __shfl_xor(m2[qt], off, 64);
            int   oi  = __shfl_xor(i1[qt], off, 64);
            bool  lt  = om1 < m1[qt];
            float loser = lt ? m1[qt] : om1;
            m2[qt] = fminf(fminf(m2[qt], om2), loser);
            m1[qt] = lt ? om1 : m1[qt];
            i1[qt] = lt ? oi  : i1[qt];
        }
    }

    #pragma unroll
    for (int qt = 0; qt < 4; ++qt) {
        bool flag = (m2[qt] - m1[qt]) <= 0.008f;
        unsigned long long mask = __ballot(flag && (lane < 16));
        while (mask) {
            int ql = __ffsll(mask) - 1;
            mask &= mask - 1;
            int qf = qw + qt * 16 + ql;
            const float* xq = x + (size_t)qf * D;
            float bb = 3.4e38f;
            int   bq = 0;
            #pragma unroll 1
            for (int c0 = 0; c0 < 8; ++c0) {
                int kc = lane * 8 + c0;
                const float4* ep = (const float4*)(cb + (size_t)kc * D);
                float a = 0.f;
                #pragma unroll
                for (int i = 0; i < 16; ++i) {
                    float4 e = ep[i];
                    a = fmaf(xq[4 * i + 0], e.x, a);
                    a = fmaf(xq[4 * i + 1], e.y, a);
                    a = fmaf(xq[4 * i + 2], e.z, a);
                    a = fmaf(xq[4 * i + 3], e.w, a);
                }
                float dd = fmaf(-2.f, a, s_esq[kc]);
                if (dd < bb) { bb = dd; bq = kc; }
            }
            #pragma unroll
            for (int off = 1; off < 64; off <<= 1) {
                float ob = __shfl_xor(bb, off, 64);
                int   oq = __shfl_xor(bq, off, 64);
                if (ob < bb || (ob == bb && oq < bq)) { bb = ob; bq = oq; }
            }
            if (qrow == ql) i1[qt] = bq;
        }
    }

    #pragma unroll
    for (int qt = 0; qt < 4; ++qt) {
        size_t q = (size_t)(qw + qt * 16 + qrow);
        const float4* src = (const float4*)(cb + (size_t)i1[qt] * D) + kg * 4;
        float4*       dst = (float4*)(out + q * D) + kg * 4;
        #pragma unroll
        for (int s = 0; s < 4; ++s) dst[s] = src[s];
    }
}

extern "C" void kernel_launch(void* const* d_in, const int* in_sizes, int n_in,
                              void* d_out, int out_size, void* d_ws, size_t ws_size,
                              hipStream_t stream) {
    const float* x   = (const float*)d_in[0];   // [8,16384,64]
    const float* cb  = (const float*)d_in[1];   // [512,64]
    float*       out = (float*)d_out;           // [8,16384,1,64]

    const size_t need = 2048 + (size_t)K * D * 2 * 2;   // esq + eh2 + el2 = 133120 B
    if (ws_size >= need) {
        float*          esq = (float*)d_ws;
        unsigned short* eh2 = (unsigned short*)((char*)d_ws + 2048);
        unsigned short* el2 = (unsigned short*)((char*)d_ws + 2048 + K * D * 2);
        prep2b_kernel<<<8, 512, 0, stream>>>(cb, esq, eh2, el2);
        vq_mfma12<<<QTOT / 512, 1024, 0, stream>>>(x, cb, esq, eh2, el2, out);
    } else {
        vq_mfma<<<QTOT / 512, 512, 0, stream>>>(x, cb, out);
    }
}